// Round 15
// baseline (116.856 us; speedup 1.0000x reference)
//
#include <hip/hip_runtime.h>
#include <stdint.h>

// Radius-graph edge list, B=4, N=2048, cutoff 5.0.
// Output [2, B*P] int32: compacted valid edges (ascending flat index), -1 pad.
//
// Round-20: r14's fast finder + r8's compose-K2 (write-once output).
//   r14 (31.7 us, best): finder fixed via TLP (576 sliced-tile blocks), but
//   K2 still re-read 16 KB x 4096 blocks to place 12K edges over the fill.
//   r8's compose structure (edges where pos < T, -1 elsewhere; one store
//   pass, no W-W) was right; its 66.8 us was the slow WALK K1 (42.7 us),
//   now replaced by the 5 us finder.
//   K1 find (576 blk x 256): r14-validated sliced tiled finder; + LDS edge
//      tally -> one atomicAdd(&total[bid&7]) per block (8 spread lines).
//   K2 fill_compose (2047 blk x 256, 4096 ints/row each): T = sum total[8].
//      cold (base >= T, ~2043 blocks): pure -1 int4 fill, no other reads.
//      hot (~4 blocks): scan all 4096 counts -> offs LDS; per-cb pf-rank
//      (r10-14-validated O(cnt^2) order restore) writes in-span edges;
//      -1 int4 fill only for positions >= T (r8-validated straddle code).
//      Disjoint positions everywhere -> no races, no fences.
// Lessons pinned: r3 grid.sync 286us; r5 fence/nontemporal 233us; r6 barrier
// -after-fill vmcnt trap; r8 same-line atomics (use 8 lines); r9 decode
// VALU; r10/r11 pointer-chase; r12/r13 1-wave finder stalls; r14 TLP wins.

namespace {
constexpr int kB = 4;
constexpr int kN = 2048;
constexpr int kP = kN * (kN - 1) / 2;              // 2096128
constexpr long long kTotal = (long long)kB * kP;   // 8384512
constexpr float kCut2 = 25.0f;                     // 5.0^2
constexpr int kCap = 128;                          // stash slots per count-blk
constexpr int kNCBlk = 4096;                       // count-blocks (2048 pairs)
constexpr int kTile = 256;
constexpr int kNT = kN / kTile;                    // 8 tiles per dim
constexpr int kTPairs = kNT * (kNT + 1) / 2;       // 36 (ti <= tj)
constexpr int kJS = 4;                             // j-slices per tile-pair
constexpr int kSliceJ = kTile / kJS;               // 64 candidates per block
constexpr int kNF = kB * kTPairs * kJS;            // 576 finder blocks
constexpr int kChunk = 4096;                       // ints per row per K2 block
constexpr int kGrid2 = (int)(kTotal / kChunk);     // 2047 (exact)
}  // namespace

// p in [0,P) -> (i,j), i<j, triu row-major (overflow fallback only).
__device__ __forceinline__ void decode_pair(int p, int& i, int& j) {
  float t = sqrtf((float)(16769025 - 8 * p));
  int ii = (int)((4095.0f - t) * 0.5f);
  ii = ii < 0 ? 0 : (ii > kN - 2 ? kN - 2 : ii);
  while (ii > 0 && (ii * (4095 - ii)) / 2 > p) --ii;
  while (ii < kN - 2 && ((ii + 1) * (4094 - ii)) / 2 <= p) ++ii;
  i = ii;
  j = ii + 1 + (p - (ii * (4095 - ii)) / 2);
}

__device__ __forceinline__ bool pair_test(const float* __restrict__ x, int b, int p,
                                          int& gi, int& gj) {
  int i, j;
  decode_pair(p, i, j);
  const float* xb = x + (size_t)b * kN * 3;
  float dx = xb[3 * i + 0] - xb[3 * j + 0];
  float dy = xb[3 * i + 1] - xb[3 * j + 1];
  float dz = xb[3 * i + 2] - xb[3 * j + 2];
  gi = b * kN + i;
  gj = b * kN + j;
  return dx * dx + dy * dy + dz * dz <= kCut2;
}

// ---------------------------------------------------------------------------
// K1: sliced tiled finder (r14-validated) + per-block total tally.
// ---------------------------------------------------------------------------
__global__ __launch_bounds__(256) void find_kernel(
    const float* __restrict__ x, uint32_t* __restrict__ counts,
    uint32_t* __restrict__ total, int2* __restrict__ stash) {
  const int t = threadIdx.x;
  const int bid = blockIdx.x;

  __shared__ float4 sp[kSliceJ];  // 64 staged j-candidates
  __shared__ uint32_t blkEdges;

  const int b = bid / (kTPairs * kJS);
  const int rem = bid - b * (kTPairs * kJS);
  const int u = rem / kJS;
  const int js = rem - u * kJS;
  int ti = 0, rowlen = kNT, acc = 0;
  while (acc + rowlen <= u) { acc += rowlen; --rowlen; ++ti; }
  const int tj = ti + (u - acc);

  const float3* __restrict__ xb3 = (const float3*)(x + (size_t)b * kN * 3);
  const int jbase = tj * kTile + js * kSliceJ;  // first j of this slice
  if (t < kSliceJ) {
    const float3 pj = xb3[jbase + t];
    sp[t] = make_float4(pj.x, pj.y, pj.z, 0.0f);
  }
  if (t == 0) blkEdges = 0;
  const int i = ti * kTile + t;
  const float3 pi = xb3[i];
  __syncthreads();

  const int gib = b << 11;            // global point-index base of batch b
  const uint32_t Ci = (uint32_t)((i * (4095 - i)) >> 1);  // C(i)
  const int cbb = b << 10;            // count-block base of batch b
  const bool diag = (ti == tj);       // block-uniform
  const int jrel0 = js * kSliceJ;     // j offset of slice start within tile

  auto emit = [&](uint32_t m, int jb0) {
    do {
      const int k = __ffs(m) - 1;
      m &= m - 1;
      const int j = jbase + jb0 + k;
      const uint32_t pf = Ci + (uint32_t)(j - i - 1);
      const int cb = cbb + (int)(pf >> 11);
      const uint32_t slot = atomicAdd(&counts[cb], 1u);
      if (slot < (uint32_t)kCap)
        stash[(size_t)cb * kCap + slot] = make_int2(gib + i, gib + j);
      atomicAdd(&blkEdges, 1u);
    } while (m);
  };

#pragma unroll
  for (int jb = 0; jb < kSliceJ; jb += 8) {
    uint32_t m = 0;
#pragma unroll
    for (int k = 0; k < 8; ++k) {
      const float4 c = sp[jb + k];
      const float dx = pi.x - c.x;
      const float dy = pi.y - c.y;
      const float dz = pi.z - c.z;
      const bool hit = (dx * dx + dy * dy + dz * dz <= kCut2) &&
                       (!diag || (jrel0 + jb + k) > t);
      m |= (uint32_t)hit << k;
    }
    if (m) emit(m, jb);
  }

  __syncthreads();
  if (t == 0 && blkEdges) atomicAdd(&total[bid & 7], blkEdges);  // 8 lines
}

// ---------------------------------------------------------------------------
// K2: compose-and-store (r8 structure). Cold: pure -1 fill. Hot (~4 blocks):
// scan counts -> offs; per-cb pf-rank writes in-span edges; -1 only >= T.
// ---------------------------------------------------------------------------
__global__ __launch_bounds__(256) void fill_compose_kernel(
    const float* __restrict__ x, const uint32_t* __restrict__ counts,
    const uint32_t* __restrict__ total, const int2* __restrict__ stash,
    int* __restrict__ out) {
  const int t = threadIdx.x;
  const int wave = t >> 6, lane = t & 63;
  const int bid = blockIdx.x;
  const int base = bid * kChunk;  // int position within each row

  uint32_t T;
  {
    const uint4* t4 = (const uint4*)total;
    uint4 a = t4[0], bb = t4[1];
    T = a.x + a.y + a.z + a.w + bb.x + bb.y + bb.z + bb.w;
  }

  int4* o0 = (int4*)out + (base >> 2);
  int4* o1 = (int4*)(out + kTotal) + (base >> 2);

  if ((uint32_t)base >= T) {  // cold path: ~2043 of 2047 blocks
    const int4 m1 = make_int4(-1, -1, -1, -1);
#pragma unroll
    for (int s = 0; s < 4; ++s) {
      o0[t + s * 256] = m1;
      o1[t + s * 256] = m1;
    }
    return;
  }

  // ---- Hot path ----
  __shared__ uint32_t offs[kNCBlk];  // 16 KB
  __shared__ uint32_t wred[4];
  {
    // Exclusive scan of 4096 counts (16/thread).
    uint32_t c[16];
    const uint4* c4 = (const uint4*)counts;
    uint32_t tsum = 0;
#pragma unroll
    for (int q = 0; q < 4; ++q) {
      uint4 v = c4[t * 4 + q];
      c[q * 4 + 0] = v.x; c[q * 4 + 1] = v.y;
      c[q * 4 + 2] = v.z; c[q * 4 + 3] = v.w;
      tsum += v.x + v.y + v.z + v.w;
    }
    uint32_t run = tsum;  // inclusive wave scan of per-thread sums
    for (int o = 1; o < 64; o <<= 1) {
      uint32_t u = __shfl_up(run, o, 64);
      if (lane >= o) run += u;
    }
    if (lane == 63) wred[wave] = run;
    __syncthreads();
    uint32_t wb = 0;
    for (int w = 0; w < 4; ++w)
      if (w < wave) wb += wred[w];
    uint32_t excl = wb + run - tsum;
#pragma unroll
    for (int q = 0; q < 16; ++q) {
      offs[t * 16 + q] = excl;
      excl += c[q];
    }
  }
  __syncthreads();

  const uint32_t spanEnd = (uint32_t)base + (uint32_t)kChunk;

  // Edges landing in this span: walk cbs (strided; offs monotone -> break).
  for (int cb = t; cb < kNCBlk; cb += 256) {
    const uint32_t o = offs[cb];
    if (o >= spanEnd) break;
    const uint32_t cnt = counts[cb];
    if (cnt == 0 || o + cnt <= (uint32_t)base) continue;

    if (cnt <= (uint32_t)kCap) {
      // pf-rank order restore (r10-14-validated): entry f -> pos o + rank_f.
      for (uint32_t f = 0; f < cnt; ++f) {
        const int2 vf = stash[(size_t)cb * kCap + f];
        const int fi = vf.x & 2047, fj = vf.y & 2047;
        const uint32_t pff = (uint32_t)((fi * (4095 - fi)) / 2 + (fj - fi - 1));
        uint32_t rank = 0;
        for (uint32_t g = 0; g < cnt; ++g) {
          const int2 vg = stash[(size_t)cb * kCap + g];
          const int gi2 = vg.x & 2047, gj2 = vg.y & 2047;
          const uint32_t pfg =
              (uint32_t)((gi2 * (4095 - gi2)) / 2 + (gj2 - gi2 - 1));
          rank += (pfg < pff) ? 1u : 0u;
        }
        const uint32_t pos = o + rank;
        if (pos >= (uint32_t)base && pos < spanEnd) {
          out[pos] = vf.x;
          out[(size_t)kTotal + pos] = vf.y;
        }
      }
    } else {
      // Never-path (cnt > kCap): serial pf-ordered rewalk of the cb's range.
      const int b_ = cb >> 10;
      const int p0 = (cb & 1023) << 11;
      uint32_t seen = 0;
      for (int p = p0; p < p0 + 2048 && p < kP; ++p) {
        int gi_, gj_;
        if (pair_test(x, b_, p, gi_, gj_)) {
          const uint32_t pos = o + seen;
          if (pos >= (uint32_t)base && pos < spanEnd) {
            out[pos] = gi_;
            out[(size_t)kTotal + pos] = gj_;
          }
          ++seen;
        }
      }
    }
  }

  // -1 fill for positions >= T within the span (r8-validated straddle).
  {
    const int4 m1 = make_int4(-1, -1, -1, -1);
#pragma unroll
    for (int r = 0; r < 2; ++r) {
      int* __restrict__ row = out + (size_t)r * kTotal;
#pragma unroll
      for (int s = 0; s < 4; ++s) {
        const int f = base + ((s * 256 + t) << 2);
        if ((uint32_t)f >= T) {
          *(int4*)(row + f) = m1;
        } else if ((uint32_t)f + 4u > T) {  // straddles the boundary
          for (int e = 0; e < 4; ++e)
            if ((uint32_t)(f + e) >= T) row[f + e] = -1;
        }
      }
    }
  }
}

extern "C" void kernel_launch(void* const* d_in, const int* in_sizes, int n_in,
                              void* d_out, int out_size, void* d_ws, size_t ws_size,
                              hipStream_t stream) {
  const float* x = (const float*)d_in[0];
  int* out = (int*)d_out;
  uint32_t* counts = (uint32_t*)d_ws;           // [4096]
  uint32_t* total = counts + kNCBlk;            // [8]
  int2* stash = (int2*)(counts + kNCBlk + 8);   // [4096 * 128] = 4 MB

  (void)hipMemsetAsync(counts, 0, (kNCBlk + 8) * sizeof(uint32_t), stream);
  hipLaunchKernelGGL(find_kernel, dim3(kNF), dim3(256), 0, stream, x, counts,
                     total, stash);
  hipLaunchKernelGGL(fill_compose_kernel, dim3(kGrid2), dim3(256), 0, stream, x,
                     counts, total, stash, out);
}

// Round 16
// 76.005 us; speedup vs baseline: 1.5375x; 1.5375x over previous
//
#include <hip/hip_runtime.h>
#include <stdint.h>

// Radius-graph edge list, B=4, N=2048, cutoff 5.0.
// Output [2, B*P] int32: compacted valid edges (ascending flat index), -1 pad.
//
// Round-21: r14 (31.7 us, best) + ONE change: hierarchical prefix.
//   Finder emits each edge with TWO spread atomics: counts[cb] (4096 words)
//   and coarse[cb>>6] (64 words; ~190 adds/word, negligible serialization).
//   K2's offset = sum(coarse[< bid>>6]) + sum(counts[(bid&~63)..bid-1]):
//   two <=63-element loads + one 64-lane butterfly instead of a 16 KB scan
//   (r14: 1 us critical path AND 64 MB aggregate L2 across 4096 blocks).
//   Everything else is r14 byte-identical (validated).
// r15 lesson (3rd confirmation of the straggler law): a handful of blocks
// doing serial pointer-chase work dominates the kernel (fill_compose: 2043
// cold blocks done in 15 us, 4 hot blocks ran 85 us at 0.3% VALUBusy).
// Other pinned lessons: r3 grid.sync 286us; r5 fence/nontemporal 233us; r6
// barrier-after-fill vmcnt trap; r8 same-WORD atomics serialize (~2047 adds
// -> +10us); r9 decode VALU; r10/r11 pointer-chase; r12/r13 1-wave finder
// stalls; r14 TLP wins.

namespace {
constexpr int kB = 4;
constexpr int kN = 2048;
constexpr int kP = kN * (kN - 1) / 2;              // 2096128
constexpr long long kTotal = (long long)kB * kP;   // 8384512
constexpr float kCut2 = 25.0f;                     // 5.0^2
constexpr int kCap = 128;                          // stash slots per count-blk
constexpr int kNCBlk = 4096;                       // count-blocks (2048 pairs)
constexpr int kNCoarse = kNCBlk / 64;              // 64 coarse bins
constexpr int kTile = 256;
constexpr int kNT = kN / kTile;                    // 8 tiles per dim
constexpr int kTPairs = kNT * (kNT + 1) / 2;       // 36 (ti <= tj)
constexpr int kJS = 4;                             // j-slices per tile-pair
constexpr int kSliceJ = kTile / kJS;               // 64 candidates per block
constexpr int kNF = kB * kTPairs * kJS;            // 576 finder blocks
constexpr int kFillBlk = 2048;
constexpr int kGrid1 = kNF + kFillBlk;             // 2624
constexpr int kFillN4 = (int)(2 * kTotal / 4);     // 4192256 int4s
constexpr int kFillPerBlk = 2048;                  // int4s per fill block
}  // namespace

// p in [0,P) -> (i,j), i<j, triu row-major (scatter fallback path only).
__device__ __forceinline__ void decode_pair(int p, int& i, int& j) {
  float t = sqrtf((float)(16769025 - 8 * p));
  int ii = (int)((4095.0f - t) * 0.5f);
  ii = ii < 0 ? 0 : (ii > kN - 2 ? kN - 2 : ii);
  while (ii > 0 && (ii * (4095 - ii)) / 2 > p) --ii;
  while (ii < kN - 2 && ((ii + 1) * (4094 - ii)) / 2 <= p) ++ii;
  i = ii;
  j = ii + 1 + (p - (ii * (4095 - ii)) / 2);
}

__device__ __forceinline__ bool pair_test(const float* __restrict__ x, int b, int p,
                                          int& gi, int& gj) {
  int i, j;
  decode_pair(p, i, j);
  const float* xb = x + (size_t)b * kN * 3;
  float dx = xb[3 * i + 0] - xb[3 * j + 0];
  float dy = xb[3 * i + 1] - xb[3 * j + 1];
  float dz = xb[3 * i + 2] - xb[3 * j + 2];
  gi = b * kN + i;
  gj = b * kN + j;
  return dx * dx + dy * dy + dz * dz <= kCut2;
}

// ---------------------------------------------------------------------------
// K1: blocks 0..575 = sliced tiled finder (r14-validated); blocks 576.. =
// contiguous -1 fill stream.
// ---------------------------------------------------------------------------
__global__ __launch_bounds__(256) void fill_find_kernel(
    const float* __restrict__ x, uint32_t* __restrict__ counts,
    uint32_t* __restrict__ coarse, int2* __restrict__ stash,
    int* __restrict__ out) {
  const int t = threadIdx.x;
  const int bid = blockIdx.x;

  if (bid >= kNF) {
    // Filler: contiguous 32 KB chunk of -1; stores issue from cycle 0,
    // nothing follows them (no barrier trap).
    const int4 m1 = make_int4(-1, -1, -1, -1);
    int4* o = (int4*)out;
    const int base = (bid - kNF) * kFillPerBlk;
#pragma unroll
    for (int s = 0; s < 8; ++s) {
      const int idx = base + s * 256 + t;
      if (idx < kFillN4) o[idx] = m1;
    }
    return;
  }

  // ---- Finder: block = (batch b, tile-pair u (ti<=tj), j-slice js) ----
  __shared__ float4 sp[kSliceJ];  // 64 staged j-candidates

  const int b = bid / (kTPairs * kJS);
  const int rem = bid - b * (kTPairs * kJS);
  const int u = rem / kJS;
  const int js = rem - u * kJS;
  int ti = 0, rowlen = kNT, acc = 0;
  while (acc + rowlen <= u) { acc += rowlen; --rowlen; ++ti; }
  const int tj = ti + (u - acc);

  const float3* __restrict__ xb3 = (const float3*)(x + (size_t)b * kN * 3);
  const int jbase = tj * kTile + js * kSliceJ;  // first j of this slice
  if (t < kSliceJ) {
    const float3 pj = xb3[jbase + t];
    sp[t] = make_float4(pj.x, pj.y, pj.z, 0.0f);
  }
  const int i = ti * kTile + t;
  const float3 pi = xb3[i];
  __syncthreads();

  const int gib = b << 11;            // global point-index base of batch b
  const uint32_t Ci = (uint32_t)((i * (4095 - i)) >> 1);  // C(i)
  const int cbb = b << 10;            // count-block base of batch b
  const bool diag = (ti == tj);       // block-uniform
  const int jrel0 = js * kSliceJ;     // j offset of slice start within tile

  // Emission: rare (~21 edges/block). Two spread atomics per edge: fine
  // (4096 words) + coarse (64 words, ~190 adds/word -- not same-word r8).
  auto emit = [&](uint32_t m, int jb0) {
    do {
      const int k = __ffs(m) - 1;
      m &= m - 1;
      const int j = jbase + jb0 + k;
      const uint32_t pf = Ci + (uint32_t)(j - i - 1);
      const int cb = cbb + (int)(pf >> 11);
      const uint32_t slot = atomicAdd(&counts[cb], 1u);
      atomicAdd(&coarse[cb >> 6], 1u);
      if (slot < (uint32_t)kCap)
        stash[(size_t)cb * kCap + slot] = make_int2(gib + i, gib + j);
    } while (m);
  };

  // 64 candidates, batched by 8 with mask-gated emission (r14-validated).
#pragma unroll
  for (int jb = 0; jb < kSliceJ; jb += 8) {
    uint32_t m = 0;
#pragma unroll
    for (int k = 0; k < 8; ++k) {
      const float4 c = sp[jb + k];
      const float dx = pi.x - c.x;
      const float dy = pi.y - c.y;
      const float dz = pi.z - c.z;
      const bool hit = (dx * dx + dy * dy + dz * dz <= kCut2) &&
                       (!diag || (jrel0 + jb + k) > t);
      m |= (uint32_t)hit << k;
    }
    if (m) emit(m, jb);
  }
}

// ---------------------------------------------------------------------------
// K2: scatter (r14 structure; prefix replaced by hierarchical coarse+fine
// butterfly -- no 16 KB scan, no LDS, no barrier). pf-rank order restore and
// exact brute-force fallback unchanged (validated 5x).
// ---------------------------------------------------------------------------
__global__ __launch_bounds__(256) void scatter_kernel(
    const float* __restrict__ x, const uint32_t* __restrict__ counts,
    const uint32_t* __restrict__ coarse, const int2* __restrict__ stash,
    int* __restrict__ out) {
  const int bid = blockIdx.x;
  const int t = threadIdx.x;

  const uint32_t cnt = counts[bid];
  if (cnt == 0) return;  // ~5% of blocks (Poisson lambda ~3)

  // Hierarchical prefix: off = sum(coarse[0..G-1]) + sum(counts[G*64..bid-1]).
  // Every wave computes it redundantly (L1-broadcast loads, no LDS/barrier).
  const int lane = t & 63;
  const int G = bid >> 6;   // coarse bin
  const int F = bid & 63;   // fine position within bin
  uint32_t a = 0;
  if (lane < G) a = coarse[lane];
  if (lane < F) a += counts[(G << 6) + lane];
  for (int o = 32; o > 0; o >>= 1) a += __shfl_xor(a, o, 64);
  const uint32_t off = a;  // identical in all lanes and waves

  if (cnt <= (uint32_t)kCap) {
    __shared__ int2 ebuf[kCap];
    __shared__ uint32_t pfb[kCap];
    for (uint32_t e = t; e < cnt; e += 256) {
      int2 v = stash[(size_t)bid * kCap + e];
      ebuf[e] = v;
      int i = v.x & 2047, j = v.y & 2047;
      pfb[e] = (uint32_t)((i * (4095 - i)) / 2 + (j - i - 1));
    }
    __syncthreads();
    for (uint32_t e = t; e < cnt; e += 256) {
      uint32_t mypf = pfb[e];
      uint32_t rank = 0;
      for (uint32_t f = 0; f < cnt; ++f) rank += (pfb[f] < mypf) ? 1u : 0u;
      out[off + rank] = ebuf[e].x;
      out[(size_t)kTotal + off + rank] = ebuf[e].y;
    }
    return;
  }

  // Fallback (cnt > kCap, never in practice): exact ballot recompute of this
  // count-block's 2048-pair range.
  const int wave = t >> 6;
  const int b = bid >> 10;
  const int p0 = (bid & 1023) << 11;
  __shared__ uint32_t slot[32];
  unsigned long long masks[8];
  int gi[8], gj[8];
  bool fl[8];
#pragma unroll
  for (int k = 0; k < 8; ++k) {
    int p = p0 + k * 256 + t;
    fl[k] = (p < kP) && pair_test(x, b, p, gi[k], gj[k]);
    masks[k] = __ballot(fl[k]);
    if (lane == 0) slot[k * 4 + wave] = (uint32_t)__popcll(masks[k]);
  }
  __syncthreads();
  if (t == 0) {
    uint32_t run = 0;
    for (int s = 0; s < 32; ++s) {
      uint32_t c = slot[s];
      slot[s] = run;
      run += c;
    }
  }
  __syncthreads();
#pragma unroll
  for (int k = 0; k < 8; ++k) {
    if (fl[k]) {
      uint32_t pos = off + slot[k * 4 + wave] +
                     (uint32_t)__popcll(masks[k] & ((1ULL << lane) - 1ULL));
      out[pos] = gi[k];
      out[(size_t)kTotal + pos] = gj[k];
    }
  }
}

extern "C" void kernel_launch(void* const* d_in, const int* in_sizes, int n_in,
                              void* d_out, int out_size, void* d_ws, size_t ws_size,
                              hipStream_t stream) {
  const float* x = (const float*)d_in[0];
  int* out = (int*)d_out;
  uint32_t* counts = (uint32_t*)d_ws;               // [4096]
  uint32_t* coarse = counts + kNCBlk;               // [64]
  int2* stash = (int2*)(counts + kNCBlk + kNCoarse);  // [4096 * 128] = 4 MB

  (void)hipMemsetAsync(counts, 0, (kNCBlk + kNCoarse) * sizeof(uint32_t), stream);
  hipLaunchKernelGGL(fill_find_kernel, dim3(kGrid1), dim3(256), 0, stream, x,
                     counts, coarse, stash, out);
  hipLaunchKernelGGL(scatter_kernel, dim3(kNCBlk), dim3(256), 0, stream, x, counts,
                     coarse, stash, out);
}

// Round 17
// 40.131 us; speedup vs baseline: 2.9119x; 1.8940x over previous
//
#include <hip/hip_runtime.h>
#include <stdint.h>

// Radius-graph edge list, B=4, N=2048, cutoff 5.0.
// Output [2, B*P] int32: compacted valid edges (ascending flat index), -1 pad.
//
// Round-22: dependency inversion. r14 (31.7 us, best) serialized:
//   K1 = max(67MB fill, finder) -> FULL DRAIN -> K2 scatter (~7 us).
// But K2 only needs counts/stash (~100 KB, ready ~5 us into K1). Fill and
// scatter write DISJOINT ranges (fill >= T, scatter < T), so:
//   K1 find (576 blk): r14-validated sliced tiled finder + r15-validated
//      total[bid&7] tally (576 end-of-block atomics over 8 words, spread in
//      time -- NOT r16's 12K-burst storm).
//   K2 fill_scatter (6144 blk): blocks 0-2047 = -1 fill clamped to >= T
//      (T = one 32B L2-hot read, not r7's 16KB prefix-before-fill mistake);
//      blocks 2048-6143 = r14 scatter byte-identical (16KB prefix, pf-rank
//      order restore, exact fallback). Scatter hides under the fill stream.
// Pinned lessons: r3 grid.sync 286us; r5 fence/nontemporal 233us; r6
// barrier-after-fill vmcnt trap; r8/r16 contended atomics cost ~ arrival
// rate per line (12K burst over 16 lines = +45us!); r9 decode VALU; r10/r11
// pointer-chase; r12/r13 1-wave finder stalls; r14 TLP wins; r15 straggler
// law (few serial blocks dominate).

namespace {
constexpr int kB = 4;
constexpr int kN = 2048;
constexpr int kP = kN * (kN - 1) / 2;              // 2096128
constexpr long long kTotal = (long long)kB * kP;   // 8384512
constexpr int kTotInt = (int)kTotal;               // fits int32
constexpr float kCut2 = 25.0f;                     // 5.0^2
constexpr int kCap = 128;                          // stash slots per count-blk
constexpr int kNCBlk = 4096;                       // count-blocks (2048 pairs)
constexpr int kTile = 256;
constexpr int kNT = kN / kTile;                    // 8 tiles per dim
constexpr int kTPairs = kNT * (kNT + 1) / 2;       // 36 (ti <= tj)
constexpr int kJS = 4;                             // j-slices per tile-pair
constexpr int kSliceJ = kTile / kJS;               // 64 candidates per block
constexpr int kNF = kB * kTPairs * kJS;            // 576 finder blocks
constexpr int kFillBlk = 2048;                     // fill blocks in K2
constexpr int kGrid2 = kFillBlk + kNCBlk;          // 6144
}  // namespace

// p in [0,P) -> (i,j), i<j, triu row-major (scatter fallback path only).
__device__ __forceinline__ void decode_pair(int p, int& i, int& j) {
  float t = sqrtf((float)(16769025 - 8 * p));
  int ii = (int)((4095.0f - t) * 0.5f);
  ii = ii < 0 ? 0 : (ii > kN - 2 ? kN - 2 : ii);
  while (ii > 0 && (ii * (4095 - ii)) / 2 > p) --ii;
  while (ii < kN - 2 && ((ii + 1) * (4094 - ii)) / 2 <= p) ++ii;
  i = ii;
  j = ii + 1 + (p - (ii * (4095 - ii)) / 2);
}

__device__ __forceinline__ bool pair_test(const float* __restrict__ x, int b, int p,
                                          int& gi, int& gj) {
  int i, j;
  decode_pair(p, i, j);
  const float* xb = x + (size_t)b * kN * 3;
  float dx = xb[3 * i + 0] - xb[3 * j + 0];
  float dy = xb[3 * i + 1] - xb[3 * j + 1];
  float dz = xb[3 * i + 2] - xb[3 * j + 2];
  gi = b * kN + i;
  gj = b * kN + j;
  return dx * dx + dy * dy + dz * dz <= kCut2;
}

// ---------------------------------------------------------------------------
// K1: sliced tiled finder (r14-validated) + total tally (r15-validated).
// ---------------------------------------------------------------------------
__global__ __launch_bounds__(256) void find_kernel(
    const float* __restrict__ x, uint32_t* __restrict__ counts,
    uint32_t* __restrict__ total, int2* __restrict__ stash) {
  const int t = threadIdx.x;
  const int bid = blockIdx.x;

  __shared__ float4 sp[kSliceJ];  // 64 staged j-candidates
  __shared__ uint32_t blkEdges;

  const int b = bid / (kTPairs * kJS);
  const int rem = bid - b * (kTPairs * kJS);
  const int u = rem / kJS;
  const int js = rem - u * kJS;
  int ti = 0, rowlen = kNT, acc = 0;
  while (acc + rowlen <= u) { acc += rowlen; --rowlen; ++ti; }
  const int tj = ti + (u - acc);

  const float3* __restrict__ xb3 = (const float3*)(x + (size_t)b * kN * 3);
  const int jbase = tj * kTile + js * kSliceJ;  // first j of this slice
  if (t < kSliceJ) {
    const float3 pj = xb3[jbase + t];
    sp[t] = make_float4(pj.x, pj.y, pj.z, 0.0f);
  }
  if (t == 0) blkEdges = 0;
  const int i = ti * kTile + t;
  const float3 pi = xb3[i];
  __syncthreads();

  const int gib = b << 11;            // global point-index base of batch b
  const uint32_t Ci = (uint32_t)((i * (4095 - i)) >> 1);  // C(i)
  const int cbb = b << 10;            // count-block base of batch b
  const bool diag = (ti == tj);       // block-uniform
  const int jrel0 = js * kSliceJ;     // j offset of slice start within tile

  // Emission: rare (~21 edges/block); single spread fine atomic per edge
  // (4096 words) + LDS tally. NO coarse array (r16: burst storm = +45us).
  auto emit = [&](uint32_t m, int jb0) {
    uint32_t n = 0;
    do {
      const int k = __ffs(m) - 1;
      m &= m - 1;
      ++n;
      const int j = jbase + jb0 + k;
      const uint32_t pf = Ci + (uint32_t)(j - i - 1);
      const int cb = cbb + (int)(pf >> 11);
      const uint32_t slot = atomicAdd(&counts[cb], 1u);
      if (slot < (uint32_t)kCap)
        stash[(size_t)cb * kCap + slot] = make_int2(gib + i, gib + j);
    } while (m);
    atomicAdd(&blkEdges, n);
  };

#pragma unroll
  for (int jb = 0; jb < kSliceJ; jb += 8) {
    uint32_t m = 0;
#pragma unroll
    for (int k = 0; k < 8; ++k) {
      const float4 c = sp[jb + k];
      const float dx = pi.x - c.x;
      const float dy = pi.y - c.y;
      const float dz = pi.z - c.z;
      const bool hit = (dx * dx + dy * dy + dz * dz <= kCut2) &&
                       (!diag || (jrel0 + jb + k) > t);
      m |= (uint32_t)hit << k;
    }
    if (m) emit(m, jb);
  }

  __syncthreads();
  // One atomic per block (576 total over 8 words, spread in time): fine.
  if (t == 0 && blkEdges) atomicAdd(&total[bid & 7], blkEdges);
}

// ---------------------------------------------------------------------------
// K2: fill (>= T) in parallel with scatter (< T). Disjoint writes, no races.
// ---------------------------------------------------------------------------
__global__ __launch_bounds__(256) void fill_scatter_kernel(
    const float* __restrict__ x, const uint32_t* __restrict__ counts,
    const uint32_t* __restrict__ total, const int2* __restrict__ stash,
    int* __restrict__ out) {
  const int t = threadIdx.x;
  const int bid = blockIdx.x;

  if (bid < kFillBlk) {
    // ---- Fill block: -1 over positions >= T of both rows (r7-validated
    // clamp/straddle). T = one 32B L2-hot read; no 16KB prefix (r7 lesson).
    uint32_t T;
    {
      const uint4* t4 = (const uint4*)total;
      const uint4 a = t4[0], b4 = t4[1];
      T = a.x + a.y + a.z + a.w + b4.x + b4.y + b4.z + b4.w;
    }
    const int4 m1 = make_int4(-1, -1, -1, -1);
    const int base = bid * 4096;  // int position within each row
#pragma unroll
    for (int s = 0; s < 4; ++s) {
      const int f = base + ((s * 256 + t) << 2);
      if (f >= kTotInt) break;
      if ((uint32_t)f >= T) {
        *(int4*)(out + f) = m1;
        *(int4*)(out + kTotal + f) = m1;
      } else if ((uint32_t)f + 4u > T) {  // straddles the boundary
        for (int e = 0; e < 4; ++e) {
          if ((uint32_t)(f + e) >= T) {
            out[f + e] = -1;
            out[kTotal + f + e] = -1;
          }
        }
      }
    }
    return;
  }

  // ---- Scatter block (r14 byte-identical, validated). ----
  const int sbid = bid - kFillBlk;

  const uint32_t cnt = counts[sbid];
  if (cnt == 0) return;

  const uint4* c4 = (const uint4*)counts;  // exactly 4096 entries
  uint32_t part = 0;
#pragma unroll
  for (int q = 0; q < 4; ++q) {
    uint4 v = c4[t * 4 + q];
    int i0 = t * 16 + q * 4;
    part += (i0 + 0 < sbid) ? v.x : 0u;
    part += (i0 + 1 < sbid) ? v.y : 0u;
    part += (i0 + 2 < sbid) ? v.z : 0u;
    part += (i0 + 3 < sbid) ? v.w : 0u;
  }
  for (int o = 32; o > 0; o >>= 1) part += __shfl_down(part, o, 64);
  __shared__ uint32_t wred[4];
  if ((t & 63) == 0) wred[t >> 6] = part;
  __syncthreads();
  if (t == 0) wred[0] = wred[0] + wred[1] + wred[2] + wred[3];
  __syncthreads();
  const uint32_t off = wred[0];

  if (cnt <= (uint32_t)kCap) {
    __shared__ int2 ebuf[kCap];
    __shared__ uint32_t pfb[kCap];
    for (uint32_t e = t; e < cnt; e += 256) {
      int2 v = stash[(size_t)sbid * kCap + e];
      ebuf[e] = v;
      int i = v.x & 2047, j = v.y & 2047;
      pfb[e] = (uint32_t)((i * (4095 - i)) / 2 + (j - i - 1));
    }
    __syncthreads();
    for (uint32_t e = t; e < cnt; e += 256) {
      uint32_t mypf = pfb[e];
      uint32_t rank = 0;
      for (uint32_t f = 0; f < cnt; ++f) rank += (pfb[f] < mypf) ? 1u : 0u;
      out[off + rank] = ebuf[e].x;
      out[(size_t)kTotal + off + rank] = ebuf[e].y;
    }
    return;
  }

  // Fallback (cnt > kCap, never in practice): exact ballot recompute of this
  // count-block's 2048-pair range.
  const int wave = t >> 6, lane = t & 63;
  const int b = sbid >> 10;
  const int p0 = (sbid & 1023) << 11;
  __shared__ uint32_t slot[32];
  unsigned long long masks[8];
  int gi[8], gj[8];
  bool fl[8];
#pragma unroll
  for (int k = 0; k < 8; ++k) {
    int p = p0 + k * 256 + t;
    fl[k] = (p < kP) && pair_test(x, b, p, gi[k], gj[k]);
    masks[k] = __ballot(fl[k]);
    if (lane == 0) slot[k * 4 + wave] = (uint32_t)__popcll(masks[k]);
  }
  __syncthreads();
  if (t == 0) {
    uint32_t run = 0;
    for (int s = 0; s < 32; ++s) {
      uint32_t c = slot[s];
      slot[s] = run;
      run += c;
    }
  }
  __syncthreads();
#pragma unroll
  for (int k = 0; k < 8; ++k) {
    if (fl[k]) {
      uint32_t pos = off + slot[k * 4 + wave] +
                     (uint32_t)__popcll(masks[k] & ((1ULL << lane) - 1ULL));
      out[pos] = gi[k];
      out[(size_t)kTotal + pos] = gj[k];
    }
  }
}

extern "C" void kernel_launch(void* const* d_in, const int* in_sizes, int n_in,
                              void* d_out, int out_size, void* d_ws, size_t ws_size,
                              hipStream_t stream) {
  const float* x = (const float*)d_in[0];
  int* out = (int*)d_out;
  uint32_t* counts = (uint32_t*)d_ws;           // [4096]
  uint32_t* total = counts + kNCBlk;            // [8]
  int2* stash = (int2*)(counts + kNCBlk + 8);   // [4096 * 128] = 4 MB

  (void)hipMemsetAsync(counts, 0, (kNCBlk + 8) * sizeof(uint32_t), stream);
  hipLaunchKernelGGL(find_kernel, dim3(kNF), dim3(256), 0, stream, x, counts,
                     total, stash);
  hipLaunchKernelGGL(fill_scatter_kernel, dim3(kGrid2), dim3(256), 0, stream, x,
                     counts, total, stash, out);
}